// Round 5
// baseline (118.675 us; speedup 1.0000x reference)
//
#include <hip/hip_runtime.h>
#include <hip/hip_bf16.h>
#include <stdint.h>

#define N_NODES 4096
#define N_EDGES 131072
#define C_IN 256
#define C_OUT 256
#define N_HEADS 4
#define C_HEAD 64
#define MAX_DEG 128

typedef __attribute__((ext_vector_type(8))) short short8;
typedef __attribute__((ext_vector_type(4))) float floatx4;

__device__ __forceinline__ short f2bf(float f) {
    __hip_bfloat16 h = __float2bfloat16(f);
    return *reinterpret_cast<short*>(&h);
}

// ---- 0. dtype probe: are float inputs fp32 (flag=1) or bf16 (flag=0)? ----
__global__ void detect_dtype(const uint32_t* __restrict__ xw, int* __restrict__ flag) {
    if (threadIdx.x == 0 && blockIdx.x == 0) {
        int hits = 0;
        for (int q = 0; q < 64; ++q) {
            uint32_t e = ((xw[q] & 0xFFFFu) >> 7) & 0xFFu;
            if (e >= 96u && e <= 144u) ++hits;
        }
        *flag = (hits >= 32) ? 0 : 1;
    }
}

// ---- 1. edge scatter into capped CSR (dedup at aggregation) ----
__global__ void scatter_edges(const int* __restrict__ ei,
                              unsigned short* __restrict__ nbr,
                              int* __restrict__ deg) {
    int e = blockIdx.x * blockDim.x + threadIdx.x;
    if (e >= N_EDGES) return;
    // int64 edge_index (ref dtype): odd int32 words (high halves) are all 0.
    bool is64 = true;
    #pragma unroll
    for (int q = 1; q < 64; q += 2) is64 = is64 && (ei[q] == 0);
    int row, col;
    if (is64) {
        const long long* e64 = (const long long*)ei;
        row = (int)e64[e];            // edge_index[0, e] -> output row i
        col = (int)e64[N_EDGES + e];  // edge_index[1, e] -> neighbor j
    } else {
        row = ei[e];
        col = ei[N_EDGES + e];
    }
    int pos = atomicAdd(&deg[row], 1);
    if (pos < MAX_DEG) nbr[row * MAX_DEG + pos] = (unsigned short)col;
}

// ---- 2. feats = x @ W^T + b   (bf16 MFMA, fp32 accum, dual-dtype input) ----
__global__ __launch_bounds__(256) void gemm_feats(
    const void* __restrict__ xv, const void* __restrict__ Wv,
    const void* __restrict__ bv, const int* __restrict__ flag,
    __hip_bfloat16* __restrict__ feats)
{
    int f32 = *flag;
    int tid  = threadIdx.x;
    int lane = tid & 63;
    int wave = tid >> 6;
    int tile = blockIdx.x * 4 + wave;          // 4096 tiles
    int row0 = (tile >> 4) * 16;
    int col0 = (tile & 15) * 16;
    int r    = lane & 15;
    int quad = lane >> 4;

    floatx4 acc = {0.f, 0.f, 0.f, 0.f};
    if (f32) {
        const floatx4* ax = (const floatx4*)((const float*)xv + (size_t)(row0 + r) * C_IN);
        const floatx4* bw = (const floatx4*)((const float*)Wv + (size_t)(col0 + r) * C_IN);
        #pragma unroll
        for (int k8 = 0; k8 < 8; ++k8) {       // K=256, steps of 32; frag k = quad*8+j
            floatx4 a0 = ax[k8 * 8 + quad * 2], a1 = ax[k8 * 8 + quad * 2 + 1];
            floatx4 b0 = bw[k8 * 8 + quad * 2], b1 = bw[k8 * 8 + quad * 2 + 1];
            short8 av, bq;
            #pragma unroll
            for (int j = 0; j < 4; ++j) {
                av[j] = f2bf(a0[j]); av[4 + j] = f2bf(a1[j]);
                bq[j] = f2bf(b0[j]); bq[4 + j] = f2bf(b1[j]);
            }
            acc = __builtin_amdgcn_mfma_f32_16x16x32_bf16(av, bq, acc, 0, 0, 0);
        }
    } else {
        const short8* ax = (const short8*)((const __hip_bfloat16*)xv + (size_t)(row0 + r) * C_IN);
        const short8* bw = (const short8*)((const __hip_bfloat16*)Wv + (size_t)(col0 + r) * C_IN);
        #pragma unroll
        for (int k8 = 0; k8 < 8; ++k8) {
            short8 av = ax[k8 * 4 + quad];
            short8 bq = bw[k8 * 4 + quad];
            acc = __builtin_amdgcn_mfma_f32_16x16x32_bf16(av, bq, acc, 0, 0, 0);
        }
    }

    // C/D layout: col = lane&15, row = quad*4 + reg
    int gn = col0 + r;
    float bias = f32 ? ((const float*)bv)[gn]
                     : __bfloat162float(((const __hip_bfloat16*)bv)[gn]);
    #pragma unroll
    for (int rr = 0; rr < 4; ++rr) {
        int gm = row0 + quad * 4 + rr;
        feats[(size_t)gm * C_OUT + gn] = __float2bfloat16(acc[rr] + bias);
    }
}

// ---- 3. separable attention scores ----
__global__ void score_kernel(const __hip_bfloat16* __restrict__ feats,
                             const void* __restrict__ av_in,
                             const int* __restrict__ flag,
                             float* __restrict__ s_src,
                             float* __restrict__ s_dst)
{
    int f32 = *flag;
    int gid = blockIdx.x * blockDim.x + threadIdx.x;  // N*H = 16384
    if (gid >= N_NODES * N_HEADS) return;
    int n = gid >> 2, h = gid & 3;
    const __hip_bfloat16* f = feats + (size_t)n * C_OUT + h * C_HEAD;
    float ss = 0.f, sd = 0.f;
    if (f32) {
        const float* a0 = (const float*)av_in + h * 2 * C_HEAD;
        #pragma unroll 8
        for (int c = 0; c < C_HEAD; ++c) {
            float fv = __bfloat162float(f[c]);
            ss += fv * a0[c];
            sd += fv * a0[C_HEAD + c];
        }
    } else {
        const __hip_bfloat16* a0 = (const __hip_bfloat16*)av_in + h * 2 * C_HEAD;
        #pragma unroll 8
        for (int c = 0; c < C_HEAD; ++c) {
            float fv = __bfloat162float(f[c]);
            ss += fv * __bfloat162float(a0[c]);
            sd += fv * __bfloat162float(a0[C_HEAD + c]);
        }
    }
    s_src[gid] = ss;
    s_dst[gid] = sd;
}

// ---- 4. per-node softmax over neighbors + weighted aggregation ----
// Output stored as FP32 (the reference's output dtype).
__global__ __launch_bounds__(256) void aggregate(
    const unsigned short* __restrict__ nbr,
    const int* __restrict__ deg,
    const __hip_bfloat16* __restrict__ feats,
    const float* __restrict__ s_src,
    const float* __restrict__ s_dst,
    float* __restrict__ out)
{
    int i = blockIdx.x;
    int t = threadIdx.x;
    int h = t >> 6;

    __shared__ unsigned short lst[MAX_DEG];
    __shared__ unsigned char  ok[MAX_DEG];
    __shared__ float wk[MAX_DEG * N_HEADS];

    int n = deg[i];
    n = (n < MAX_DEG) ? n : MAX_DEG;

    if (t < n) lst[t] = nbr[i * MAX_DEG + t];
    __syncthreads();
    // dedup: keep entry k iff no earlier equal entry (matches boolean-adjacency ref)
    if (t < n) {
        unsigned short v = lst[t];
        bool keep = true;
        for (int q = 0; q < t; ++q) keep = keep && (lst[q] != v);
        ok[t] = keep ? 1 : 0;
    }
    __syncthreads();
    for (int p = t; p < n * N_HEADS; p += 256) {
        int k = p >> 2, hh = p & 3;
        float l = s_src[i * N_HEADS + hh] + s_dst[(int)lst[k] * N_HEADS + hh];
        l = (l > 0.f) ? l : 0.2f * l;            // leaky_relu, ALPHA = 0.2
        l = fminf(fmaxf(l, -60.f), 60.f);        // overflow insurance
        wk[k * N_HEADS + hh] = ok[k] ? __expf(l) : 0.f;
    }
    __syncthreads();

    float acc = 0.f, denom = 0.f;
    if (n > 0) {
        for (int k = 0; k < n; ++k) {
            float w = wk[k * N_HEADS + h];
            denom += w;
            acc += w * __bfloat162float(feats[(size_t)lst[k] * C_OUT + t]);
        }
        if (denom <= 0.f) denom = 1.f;           // unreachable guard
    } else {
        // ref: all-NEG_FILL row -> uniform softmax over every node
        for (int j = 0; j < N_NODES; ++j)
            acc += __bfloat162float(feats[(size_t)j * C_OUT + t]);
        denom = (float)N_NODES;
    }
    out[(size_t)i * C_OUT + t] = acc / denom;    // FP32 store
}

extern "C" void kernel_launch(void* const* d_in, const int* in_sizes, int n_in,
                              void* d_out, int out_size, void* d_ws, size_t ws_size,
                              hipStream_t stream) {
    const void* x  = d_in[0];
    const int*  ei = (const int*)d_in[1];
    const void* W  = d_in[2];
    const void* b  = d_in[3];
    const void* a  = d_in[4];
    float* out = (float*)d_out;

    // Workspace layout (3.19 MB):
    //   feats @ 0          : 2 MB (bf16 4096x256)
    //   nbr   @ 2 MB       : 1 MB (u16 4096x128)
    //   deg   @ 3 MB       : 16 KB
    //   s_src @ 3 MB+16K   : 64 KB
    //   s_dst @ 3 MB+80K   : 64 KB
    //   flag  @ 3 MB+144K  : 4 B
    uint8_t* ws = (uint8_t*)d_ws;
    __hip_bfloat16* feats = (__hip_bfloat16*)ws;
    unsigned short* nbr   = (unsigned short*)(ws + (2u << 20));
    int*            deg   = (int*)(ws + (3u << 20));
    float*          s_src = (float*)(ws + (3u << 20) + (16u << 10));
    float*          s_dst = (float*)(ws + (3u << 20) + (80u << 10));
    int*            flag  = (int*)(ws + (3u << 20) + (144u << 10));

    hipMemsetAsync(deg, 0, N_NODES * sizeof(int), stream);
    detect_dtype<<<1, 64, 0, stream>>>((const uint32_t*)x, flag);
    scatter_edges<<<N_EDGES / 256, 256, 0, stream>>>(ei, nbr, deg);
    gemm_feats<<<(N_NODES / 16) * (C_OUT / 16) / 4, 256, 0, stream>>>(x, W, b, flag, feats);
    score_kernel<<<N_NODES * N_HEADS / 256, 256, 0, stream>>>(feats, a, flag, s_src, s_dst);
    aggregate<<<N_NODES, 256, 0, stream>>>(nbr, deg, feats, s_src, s_dst, out);
}

// Round 6
// 111.191 us; speedup vs baseline: 1.0673x; 1.0673x over previous
//
#include <hip/hip_runtime.h>
#include <hip/hip_bf16.h>
#include <stdint.h>

#define N_NODES 4096
#define N_EDGES 131072
#define C_IN 256
#define C_OUT 256
#define N_HEADS 4
#define C_HEAD 64
#define MAX_DEG 128

typedef __attribute__((ext_vector_type(8))) short short8;
typedef __attribute__((ext_vector_type(4))) short short4v;
typedef __attribute__((ext_vector_type(4))) float floatx4;

union f32u { float f; uint32_t u; };
__device__ __forceinline__ float bf2f(short s) {
    f32u v; v.u = ((uint32_t)(uint16_t)s) << 16; return v.f;
}
__device__ __forceinline__ short f2bf(float f) {
    __hip_bfloat16 h = __float2bfloat16(f);
    return *reinterpret_cast<short*>(&h);
}

// ---- 1. edge scatter into capped CSR (dedup at aggregation) ----
__global__ void scatter_edges(const int* __restrict__ ei,
                              unsigned short* __restrict__ nbr,
                              int* __restrict__ deg) {
    int e = blockIdx.x * blockDim.x + threadIdx.x;
    if (e >= N_EDGES) return;
    // int64 edge_index (ref dtype): odd int32 words (high halves) are all 0.
    // Uniform-address reads -> scalarized by compiler; cheap.
    bool is64 = true;
    #pragma unroll
    for (int q = 1; q < 64; q += 2) is64 = is64 && (ei[q] == 0);
    int row, col;
    if (is64) {
        const long long* e64 = (const long long*)ei;
        row = (int)e64[e];            // edge_index[0, e] -> output row i
        col = (int)e64[N_EDGES + e];  // edge_index[1, e] -> neighbor j
    } else {
        row = ei[e];
        col = ei[N_EDGES + e];
    }
    int pos = atomicAdd(&deg[row], 1);
    if (pos < MAX_DEG) nbr[row * MAX_DEG + pos] = (unsigned short)col;
}

// ---- 2. feats = x @ W^T + b   (fp32 in, bf16 MFMA, fp32 accum, bf16 out) ----
__global__ __launch_bounds__(256) void gemm_feats(
    const float* __restrict__ x, const float* __restrict__ W,
    const float* __restrict__ b, __hip_bfloat16* __restrict__ feats)
{
    int tid  = threadIdx.x;
    int lane = tid & 63;
    int wave = tid >> 6;
    int tile = blockIdx.x * 4 + wave;          // 4096 tiles
    int row0 = (tile >> 4) * 16;
    int col0 = (tile & 15) * 16;
    int r    = lane & 15;
    int quad = lane >> 4;

    const floatx4* ax = (const floatx4*)(x + (size_t)(row0 + r) * C_IN);
    const floatx4* bw = (const floatx4*)(W + (size_t)(col0 + r) * C_IN);

    floatx4 acc = {0.f, 0.f, 0.f, 0.f};
    #pragma unroll
    for (int k8 = 0; k8 < 8; ++k8) {           // K=256, steps of 32; frag k = quad*8+j
        floatx4 a0 = ax[k8 * 8 + quad * 2], a1 = ax[k8 * 8 + quad * 2 + 1];
        floatx4 b0 = bw[k8 * 8 + quad * 2], b1 = bw[k8 * 8 + quad * 2 + 1];
        short8 av, bq;
        #pragma unroll
        for (int j = 0; j < 4; ++j) {
            av[j] = f2bf(a0[j]); av[4 + j] = f2bf(a1[j]);
            bq[j] = f2bf(b0[j]); bq[4 + j] = f2bf(b1[j]);
        }
        acc = __builtin_amdgcn_mfma_f32_16x16x32_bf16(av, bq, acc, 0, 0, 0);
    }

    // C/D layout: col = lane&15, row = quad*4 + reg  (HW-verified)
    int gn = col0 + r;
    float bias = b[gn];
    #pragma unroll
    for (int rr = 0; rr < 4; ++rr) {
        int gm = row0 + quad * 4 + rr;
        feats[(size_t)gm * C_OUT + gn] = __float2bfloat16(acc[rr] + bias);
    }
}

// ---- 3. separable attention scores (vectorized loads) ----
__global__ __launch_bounds__(64) void score_kernel(
    const __hip_bfloat16* __restrict__ feats, const float* __restrict__ a,
    float* __restrict__ s_src, float* __restrict__ s_dst)
{
    int gid = blockIdx.x * 64 + threadIdx.x;   // N*H = 16384
    int n = gid >> 2, h = gid & 3;
    const short8*  f  = (const short8*)(feats + (size_t)n * C_OUT + h * C_HEAD);
    const floatx4* as = (const floatx4*)(a + h * 2 * C_HEAD);
    float ss = 0.f, sd = 0.f;
    #pragma unroll
    for (int v = 0; v < 8; ++v) {              // 8 x (8 bf16 = 16B)
        short8 fv = f[v];
        floatx4 s0 = as[v * 2],      s1 = as[v * 2 + 1];
        floatx4 d0 = as[16 + v * 2], d1 = as[16 + v * 2 + 1];
        #pragma unroll
        for (int j = 0; j < 4; ++j) {
            float x0 = bf2f(fv[j]);
            float x1 = bf2f(fv[4 + j]);
            ss += x0 * s0[j] + x1 * s1[j];
            sd += x0 * d0[j] + x1 * d1[j];
        }
    }
    s_src[gid] = ss;
    s_dst[gid] = sd;
}

// ---- 4. per-node softmax + aggregation ----
// Block = 256 thr = 4 waves. Lane c (0..63) owns channels 4c..4c+3 (head c>>4).
// Wave w processes neighbors k = w, w+4, ... ; cross-wave reduce in LDS.
__global__ __launch_bounds__(256) void aggregate(
    const unsigned short* __restrict__ nbr,
    const int* __restrict__ deg,
    const __hip_bfloat16* __restrict__ feats,
    const float* __restrict__ s_src,
    const float* __restrict__ s_dst,
    float* __restrict__ out)
{
    int i    = blockIdx.x;
    int t    = threadIdx.x;
    int wv   = t >> 6;
    int lane = t & 63;
    int h    = lane >> 4;                      // head of this lane's 4 channels

    __shared__ unsigned short lst[MAX_DEG];
    __shared__ unsigned char  ok[MAX_DEG];
    __shared__ float          wk[MAX_DEG][N_HEADS];
    __shared__ floatx4        red[4][64];

    int n = deg[i];
    n = (n < MAX_DEG) ? n : MAX_DEG;

    if (t < n) lst[t] = nbr[i * MAX_DEG + t];
    __syncthreads();
    // dedup: keep entry k iff no earlier equal entry (matches boolean-adjacency ref)
    if (t < n) {
        unsigned short v = lst[t];
        bool keep = true;
        for (int q = 0; q < t; ++q) keep = keep && (lst[q] != v);
        ok[t] = keep ? 1 : 0;
    }
    __syncthreads();
    for (int p = t; p < n * N_HEADS; p += 256) {
        int k = p >> 2, hh = p & 3;
        float l = s_src[i * N_HEADS + hh] + s_dst[(int)lst[k] * N_HEADS + hh];
        l = (l > 0.f) ? l : 0.2f * l;          // leaky_relu, ALPHA = 0.2
        l = fminf(l, 60.f);                    // overflow insurance
        wk[k][hh] = ok[k] ? __expf(l) : 0.f;
    }
    __syncthreads();

    floatx4 acc = {0.f, 0.f, 0.f, 0.f};
    if (n > 0) {
        for (int k = wv; k < n; k += 4) {
            float w = wk[k][h];
            short4v fv = *(const short4v*)(feats + (size_t)lst[k] * C_OUT + lane * 4);
            acc[0] += w * bf2f(fv[0]);
            acc[1] += w * bf2f(fv[1]);
            acc[2] += w * bf2f(fv[2]);
            acc[3] += w * bf2f(fv[3]);
        }
    } else {
        // ref: all-NEG_FILL row -> uniform softmax over every node
        for (int j = wv; j < N_NODES; j += 4) {
            short4v fv = *(const short4v*)(feats + (size_t)j * C_OUT + lane * 4);
            acc[0] += bf2f(fv[0]);
            acc[1] += bf2f(fv[1]);
            acc[2] += bf2f(fv[2]);
            acc[3] += bf2f(fv[3]);
        }
    }
    red[wv][lane] = acc;
    __syncthreads();

    if (wv == 0) {
        floatx4 r0 = red[0][lane], r1 = red[1][lane], r2 = red[2][lane], r3 = red[3][lane];
        float denom;
        if (n > 0) {
            denom = 0.f;
            for (int k = 0; k < n; ++k) denom += wk[k][h];
            if (denom <= 0.f) denom = 1.f;     // unreachable guard
        } else {
            denom = (float)N_NODES;
        }
        float inv = 1.0f / denom;
        floatx4 o;
        o[0] = (r0[0] + r1[0] + r2[0] + r3[0]) * inv;
        o[1] = (r0[1] + r1[1] + r2[1] + r3[1]) * inv;
        o[2] = (r0[2] + r1[2] + r2[2] + r3[2]) * inv;
        o[3] = (r0[3] + r1[3] + r2[3] + r3[3]) * inv;
        *(floatx4*)(out + (size_t)i * C_OUT + lane * 4) = o;
    }
}

extern "C" void kernel_launch(void* const* d_in, const int* in_sizes, int n_in,
                              void* d_out, int out_size, void* d_ws, size_t ws_size,
                              hipStream_t stream) {
    const float* x  = (const float*)d_in[0];
    const int*   ei = (const int*)d_in[1];
    const float* W  = (const float*)d_in[2];
    const float* b  = (const float*)d_in[3];
    const float* a  = (const float*)d_in[4];
    float* out = (float*)d_out;

    // Workspace layout (ws_size is 256 MB; we use 3.19 MB):
    //   feats @ 0          : 2 MB (bf16 4096x256)
    //   nbr   @ 2 MB       : 1 MB (u16 4096x128)
    //   deg   @ 3 MB       : 16 KB
    //   s_src @ 3 MB+16K   : 64 KB
    //   s_dst @ 3 MB+80K   : 64 KB
    uint8_t* ws = (uint8_t*)d_ws;
    __hip_bfloat16* feats = (__hip_bfloat16*)ws;
    unsigned short* nbr   = (unsigned short*)(ws + (2u << 20));
    int*            deg   = (int*)(ws + (3u << 20));
    float*          s_src = (float*)(ws + (3u << 20) + (16u << 10));
    float*          s_dst = (float*)(ws + (3u << 20) + (80u << 10));

    hipMemsetAsync(deg, 0, N_NODES * sizeof(int), stream);
    scatter_edges<<<N_EDGES / 256, 256, 0, stream>>>(ei, nbr, deg);
    gemm_feats<<<(N_NODES / 16) * (C_OUT / 16) / 4, 256, 0, stream>>>(x, W, b, feats);
    score_kernel<<<N_NODES * N_HEADS / 64, 64, 0, stream>>>(feats, a, s_src, s_dst);
    aggregate<<<N_NODES, 256, 0, stream>>>(nbr, deg, feats, s_src, s_dst, out);
}

// Round 7
// 108.592 us; speedup vs baseline: 1.0929x; 1.0239x over previous
//
#include <hip/hip_runtime.h>
#include <hip/hip_bf16.h>
#include <stdint.h>

#define N_NODES 4096
#define N_EDGES 131072
#define C_IN 256
#define C_OUT 256
#define N_HEADS 4
#define C_HEAD 64
#define MAX_DEG 128
#define GEMM_BLOCKS 1024
#define SCAT_BLOCKS 128

typedef __attribute__((ext_vector_type(8))) short short8;
typedef __attribute__((ext_vector_type(4))) short short4v;
typedef __attribute__((ext_vector_type(4))) float floatx4;

union f32u { float f; uint32_t u; };
__device__ __forceinline__ float bf2f(short s) {
    f32u v; v.u = ((uint32_t)(uint16_t)s) << 16; return v.f;
}
__device__ __forceinline__ short f2bf(float f) {
    __hip_bfloat16 h = __float2bfloat16(f);
    return *reinterpret_cast<short*>(&h);
}

// ---- K1: scatter (blocks 1024..1151) in parallel with gemm (blocks 0..1023) ----
// gemm: feats = x @ W^T + b (fp32 in, bf16 MFMA fp32-accum, bf16 out)
// scatter: capped CSR from edge_index (dedup at aggregation)
__global__ __launch_bounds__(256) void k1_gemm_scatter(
    const float* __restrict__ x, const float* __restrict__ W,
    const float* __restrict__ b, const int* __restrict__ ei,
    unsigned short* __restrict__ nbr, int* __restrict__ deg,
    __hip_bfloat16* __restrict__ feats)
{
    int blk = blockIdx.x;
    int tid = threadIdx.x;
    if (blk < GEMM_BLOCKS) {
        int lane = tid & 63;
        int wave = tid >> 6;
        int tile = blk * 4 + wave;                 // 4096 tiles
        int row0 = (tile >> 4) * 16;
        int col0 = (tile & 15) * 16;
        int r    = lane & 15;
        int quad = lane >> 4;

        const floatx4* ax = (const floatx4*)(x + (size_t)(row0 + r) * C_IN);
        const floatx4* bw = (const floatx4*)(W + (size_t)(col0 + r) * C_IN);

        floatx4 acc = {0.f, 0.f, 0.f, 0.f};
        #pragma unroll
        for (int k8 = 0; k8 < 8; ++k8) {           // K=256, steps of 32; frag k = quad*8+j
            floatx4 a0 = ax[k8 * 8 + quad * 2], a1 = ax[k8 * 8 + quad * 2 + 1];
            floatx4 b0 = bw[k8 * 8 + quad * 2], b1 = bw[k8 * 8 + quad * 2 + 1];
            short8 av, bq;
            #pragma unroll
            for (int j = 0; j < 4; ++j) {
                av[j] = f2bf(a0[j]); av[4 + j] = f2bf(a1[j]);
                bq[j] = f2bf(b0[j]); bq[4 + j] = f2bf(b1[j]);
            }
            acc = __builtin_amdgcn_mfma_f32_16x16x32_bf16(av, bq, acc, 0, 0, 0);
        }
        // C/D layout: col = lane&15, row = quad*4 + reg (HW-verified)
        int gn = col0 + r;
        float bias = b[gn];
        #pragma unroll
        for (int rr = 0; rr < 4; ++rr) {
            int gm = row0 + quad * 4 + rr;
            feats[(size_t)gm * C_OUT + gn] = __float2bfloat16(acc[rr] + bias);
        }
    } else {
        // scatter: 128 blocks x 256 thr x 4 edges
        // int64 edge_index (ref dtype): odd int32 words are all 0 (uniform scalar loads)
        bool is64 = true;
        #pragma unroll
        for (int q = 1; q < 64; q += 2) is64 = is64 && (ei[q] == 0);
        int base = (blk - GEMM_BLOCKS) * 256 + tid;      // 0..32767
        #pragma unroll
        for (int qq = 0; qq < 4; ++qq) {
            int e = base + qq * (SCAT_BLOCKS * 256);
            int row, col;
            if (is64) {
                const long long* e64 = (const long long*)ei;
                row = (int)e64[e];            // edge_index[0, e] -> output row i
                col = (int)e64[N_EDGES + e];  // edge_index[1, e] -> neighbor j
            } else {
                row = ei[e];
                col = ei[N_EDGES + e];
            }
            int pos = atomicAdd(&deg[row], 1);
            if (pos < MAX_DEG) nbr[row * MAX_DEG + pos] = (unsigned short)col;
        }
    }
}

// ---- K2: fused scores + softmax + aggregation ----
// Block = 256 thr = 4 waves, one block per node i.
// Lane owns channels 4*lane..4*lane+3 (head h = lane>>4).
// Wave w handles neighbors k = w, w+4, ...; score f_j.a_dst computed in-loop
// via 16-lane (per-head) shfl_xor reduce; cross-wave reduce in LDS.
__global__ __launch_bounds__(256) void aggregate(
    const unsigned short* __restrict__ nbr,
    const int* __restrict__ deg,
    const __hip_bfloat16* __restrict__ feats,
    const float* __restrict__ a,
    float* __restrict__ out)
{
    int i    = blockIdx.x;
    int t    = threadIdx.x;
    int wv   = t >> 6;
    int lane = t & 63;
    int h    = lane >> 4;
    int li   = lane & 15;

    __shared__ unsigned short lst[MAX_DEG];
    __shared__ unsigned char  ok[MAX_DEG];
    __shared__ float          ssrc_sh[N_HEADS];
    __shared__ floatx4        redv[4][64];
    __shared__ float          redd[4][64];

    int n = deg[i];
    n = (n < MAX_DEG) ? n : MAX_DEG;

    if (t < n) lst[t] = nbr[i * MAX_DEG + t];
    __syncthreads();
    // dedup: keep entry k iff no earlier equal entry (matches boolean-adjacency ref)
    if (t < n) {
        unsigned short v = lst[t];
        bool keep = true;
        for (int q = 0; q < t; ++q) keep = keep && (lst[q] != v);
        ok[t] = keep ? 1 : 0;
    }

    // per-lane slices of the attention vector (a[h][0:64]=src, a[h][64:128]=dst)
    floatx4 as4 = *(const floatx4*)(a + h * 2 * C_HEAD + 4 * li);
    floatx4 ad4 = *(const floatx4*)(a + h * 2 * C_HEAD + C_HEAD + 4 * li);

    // s_src[i,h] by wave 0 (one row read + per-head reduce)
    if (wv == 0) {
        short4v fi = *(const short4v*)(feats + (size_t)i * C_OUT + lane * 4);
        float p = bf2f(fi[0]) * as4[0] + bf2f(fi[1]) * as4[1]
                + bf2f(fi[2]) * as4[2] + bf2f(fi[3]) * as4[3];
        p += __shfl_xor(p, 1, 16);
        p += __shfl_xor(p, 2, 16);
        p += __shfl_xor(p, 4, 16);
        p += __shfl_xor(p, 8, 16);
        if (li == 0) ssrc_sh[h] = p;
    }
    __syncthreads();     // publishes ok[] and ssrc_sh

    float ssrc = ssrc_sh[h];
    floatx4 acc = {0.f, 0.f, 0.f, 0.f};
    float   den = 0.f;

    if (n > 0) {
        for (int k = wv; k < n; k += 4) {
            int j = lst[k];
            short4v fv = *(const short4v*)(feats + (size_t)j * C_OUT + lane * 4);
            float f0 = bf2f(fv[0]), f1 = bf2f(fv[1]), f2 = bf2f(fv[2]), f3 = bf2f(fv[3]);
            float p = f0 * ad4[0] + f1 * ad4[1] + f2 * ad4[2] + f3 * ad4[3];
            p += __shfl_xor(p, 1, 16);
            p += __shfl_xor(p, 2, 16);
            p += __shfl_xor(p, 4, 16);
            p += __shfl_xor(p, 8, 16);          // p = f_j . a_dst[h]
            float l = ssrc + p;
            l = (l > 0.f) ? l : 0.2f * l;       // leaky_relu, ALPHA = 0.2
            float w = ok[k] ? __expf(fminf(l, 60.f)) : 0.f;
            den += w;
            acc[0] += w * f0; acc[1] += w * f1; acc[2] += w * f2; acc[3] += w * f3;
        }
    } else {
        // ref: all-NEG_FILL row -> uniform softmax over every node
        for (int j = wv; j < N_NODES; j += 4) {
            short4v fv = *(const short4v*)(feats + (size_t)j * C_OUT + lane * 4);
            acc[0] += bf2f(fv[0]); acc[1] += bf2f(fv[1]);
            acc[2] += bf2f(fv[2]); acc[3] += bf2f(fv[3]);
            den += 1.0f;
        }
    }
    redv[wv][lane] = acc;
    redd[wv][lane] = den;
    __syncthreads();

    if (wv == 0) {
        floatx4 r0 = redv[0][lane], r1 = redv[1][lane], r2 = redv[2][lane], r3 = redv[3][lane];
        float d = redd[0][lane] + redd[1][lane] + redd[2][lane] + redd[3][lane];
        if (d <= 0.f) d = 1.f;                  // unreachable guard
        float inv = 1.0f / d;
        floatx4 o;
        o[0] = (r0[0] + r1[0] + r2[0] + r3[0]) * inv;
        o[1] = (r0[1] + r1[1] + r2[1] + r3[1]) * inv;
        o[2] = (r0[2] + r1[2] + r2[2] + r3[2]) * inv;
        o[3] = (r0[3] + r1[3] + r2[3] + r3[3]) * inv;
        *(floatx4*)(out + (size_t)i * C_OUT + lane * 4) = o;
    }
}

extern "C" void kernel_launch(void* const* d_in, const int* in_sizes, int n_in,
                              void* d_out, int out_size, void* d_ws, size_t ws_size,
                              hipStream_t stream) {
    const float* x  = (const float*)d_in[0];
    const int*   ei = (const int*)d_in[1];
    const float* W  = (const float*)d_in[2];
    const float* b  = (const float*)d_in[3];
    const float* a  = (const float*)d_in[4];
    float* out = (float*)d_out;

    // Workspace layout (ws_size is 256 MB; we use ~3 MB):
    //   feats @ 0      : 2 MB (bf16 4096x256)
    //   nbr   @ 2 MB   : 1 MB (u16 4096x128)
    //   deg   @ 3 MB   : 16 KB
    uint8_t* ws = (uint8_t*)d_ws;
    __hip_bfloat16* feats = (__hip_bfloat16*)ws;
    unsigned short* nbr   = (unsigned short*)(ws + (2u << 20));
    int*            deg   = (int*)(ws + (3u << 20));

    hipMemsetAsync(deg, 0, N_NODES * sizeof(int), stream);
    k1_gemm_scatter<<<GEMM_BLOCKS + SCAT_BLOCKS, 256, 0, stream>>>(x, W, b, ei, nbr, deg, feats);
    aggregate<<<N_NODES, 256, 0, stream>>>(nbr, deg, feats, a, out);
}

// Round 9
// 102.398 us; speedup vs baseline: 1.1590x; 1.0605x over previous
//
#include <hip/hip_runtime.h>
#include <hip/hip_bf16.h>
#include <stdint.h>

#define N_NODES 4096
#define N_EDGES 131072
#define C_IN 256
#define C_OUT 256
#define N_HEADS 4
#define C_HEAD 64
#define MAX_DEG 128
#define GEMM_BLOCKS 1024
#define SCAT_BLOCKS 128

typedef __attribute__((ext_vector_type(8))) short short8;
typedef __attribute__((ext_vector_type(4))) short short4v;
typedef __attribute__((ext_vector_type(4))) float floatx4;

union f32u { float f; uint32_t u; };
__device__ __forceinline__ float bf2f(short s) {
    f32u v; v.u = ((uint32_t)(uint16_t)s) << 16; return v.f;
}
__device__ __forceinline__ short f2bf(float f) {
    __hip_bfloat16 h = __float2bfloat16(f);
    return *reinterpret_cast<short*>(&h);
}

// ---- K1: scatter (blocks 1024..1151) in parallel with gemm (blocks 0..1023) ----
// gemm: feats = x @ W^T + b (fp32 in, bf16 MFMA fp32-accum, bf16 out)
// scatter: capped CSR from edge_index (dedup at aggregation)
__global__ __launch_bounds__(256) void k1_gemm_scatter(
    const float* __restrict__ x, const float* __restrict__ W,
    const float* __restrict__ b, const int* __restrict__ ei,
    unsigned short* __restrict__ nbr, int* __restrict__ deg,
    __hip_bfloat16* __restrict__ feats)
{
    int blk = blockIdx.x;
    int tid = threadIdx.x;
    if (blk < GEMM_BLOCKS) {
        int lane = tid & 63;
        int wave = tid >> 6;
        int tile = blk * 4 + wave;                 // 4096 tiles
        int row0 = (tile >> 4) * 16;
        int col0 = (tile & 15) * 16;
        int r    = lane & 15;
        int quad = lane >> 4;

        const floatx4* ax = (const floatx4*)(x + (size_t)(row0 + r) * C_IN);
        const floatx4* bw = (const floatx4*)(W + (size_t)(col0 + r) * C_IN);

        floatx4 acc = {0.f, 0.f, 0.f, 0.f};
        #pragma unroll
        for (int k8 = 0; k8 < 8; ++k8) {           // K=256, steps of 32; frag k = quad*8+j
            floatx4 a0 = ax[k8 * 8 + quad * 2], a1 = ax[k8 * 8 + quad * 2 + 1];
            floatx4 b0 = bw[k8 * 8 + quad * 2], b1 = bw[k8 * 8 + quad * 2 + 1];
            short8 av, bq;
            #pragma unroll
            for (int j = 0; j < 4; ++j) {
                av[j] = f2bf(a0[j]); av[4 + j] = f2bf(a1[j]);
                bq[j] = f2bf(b0[j]); bq[4 + j] = f2bf(b1[j]);
            }
            acc = __builtin_amdgcn_mfma_f32_16x16x32_bf16(av, bq, acc, 0, 0, 0);
        }
        // C/D layout: col = lane&15, row = quad*4 + reg (HW-verified)
        int gn = col0 + r;
        float bias = b[gn];
        #pragma unroll
        for (int rr = 0; rr < 4; ++rr) {
            int gm = row0 + quad * 4 + rr;
            feats[(size_t)gm * C_OUT + gn] = __float2bfloat16(acc[rr] + bias);
        }
    } else {
        // scatter: 128 blocks x 256 thr x 4 edges
        // int64 edge_index (ref dtype): odd int32 words are all 0 (uniform scalar loads)
        bool is64 = true;
        #pragma unroll
        for (int q = 1; q < 64; q += 2) is64 = is64 && (ei[q] == 0);
        int base = (blk - GEMM_BLOCKS) * 256 + tid;      // 0..32767
        #pragma unroll
        for (int qq = 0; qq < 4; ++qq) {
            int e = base + qq * (SCAT_BLOCKS * 256);
            int row, col;
            if (is64) {
                const long long* e64 = (const long long*)ei;
                row = (int)e64[e];            // edge_index[0, e] -> output row i
                col = (int)e64[N_EDGES + e];  // edge_index[1, e] -> neighbor j
            } else {
                row = ei[e];
                col = ei[N_EDGES + e];
            }
            int pos = atomicAdd(&deg[row], 1);
            if (pos < MAX_DEG) nbr[row * MAX_DEG + pos] = (unsigned short)col;
        }
    }
}

// ---- K2: fused scores + softmax + aggregation ----
// Block = 256 thr = 4 waves, one block per node i.
// Lane owns channels 4*lane..4*lane+3 (head h = lane>>4).
// Wave w handles neighbors k = w, w+4, ...; score f_j.a_dst computed in-loop
// via 16-lane (per-head) shfl_xor reduce; cross-wave reduce in LDS.
// Dedup via shared bitmap + atomicOr: duplicates carry identical (j, weight),
// so keep-exactly-one == reference's boolean-adjacency semantics.
__global__ __launch_bounds__(256) void aggregate(
    const unsigned short* __restrict__ nbr,
    const int* __restrict__ deg,
    const __hip_bfloat16* __restrict__ feats,
    const float* __restrict__ a,
    float* __restrict__ out)
{
    int i    = blockIdx.x;
    int t    = threadIdx.x;
    int wv   = t >> 6;
    int lane = t & 63;
    int h    = lane >> 4;
    int li   = lane & 15;

    __shared__ unsigned short lst[MAX_DEG];
    __shared__ unsigned char  ok[MAX_DEG];
    __shared__ uint32_t       bmap[N_NODES / 32];   // 512 B
    __shared__ float          ssrc_sh[N_HEADS];
    __shared__ floatx4        redv[4][64];
    __shared__ float          redd[4][64];

    int n = deg[i];
    n = (n < MAX_DEG) ? n : MAX_DEG;

    if (t < n) lst[t] = nbr[i * MAX_DEG + t];
    if (t < N_NODES / 32) bmap[t] = 0u;
    __syncthreads();

    // O(1) dedup + s_src in the same phase
    if (t < n) {
        int j = lst[t];
        uint32_t bit = 1u << (j & 31);
        uint32_t old = atomicOr(&bmap[j >> 5], bit);
        ok[t] = (old & bit) ? 0 : 1;
    }

    // per-lane slices of the attention vector (a[h][0:64]=src, a[h][64:128]=dst)
    floatx4 as4 = *(const floatx4*)(a + h * 2 * C_HEAD + 4 * li);
    floatx4 ad4 = *(const floatx4*)(a + h * 2 * C_HEAD + C_HEAD + 4 * li);

    if (wv == 0) {   // s_src[i,h]: one row read + per-head reduce
        short4v fi = *(const short4v*)(feats + (size_t)i * C_OUT + lane * 4);
        float p = bf2f(fi[0]) * as4[0] + bf2f(fi[1]) * as4[1]
                + bf2f(fi[2]) * as4[2] + bf2f(fi[3]) * as4[3];
        p += __shfl_xor(p, 1, 16);
        p += __shfl_xor(p, 2, 16);
        p += __shfl_xor(p, 4, 16);
        p += __shfl_xor(p, 8, 16);
        if (li == 0) ssrc_sh[h] = p;
    }
    __syncthreads();     // publishes ok[] and ssrc_sh

    float ssrc = ssrc_sh[h];
    floatx4 acc = {0.f, 0.f, 0.f, 0.f};
    float   den = 0.f;

    if (n > 0) {
        #pragma unroll 2
        for (int k = wv; k < n; k += 4) {
            int j = lst[k];
            short4v fv = *(const short4v*)(feats + (size_t)j * C_OUT + lane * 4);
            float f0 = bf2f(fv[0]), f1 = bf2f(fv[1]), f2 = bf2f(fv[2]), f3 = bf2f(fv[3]);
            float p = f0 * ad4[0] + f1 * ad4[1] + f2 * ad4[2] + f3 * ad4[3];
            p += __shfl_xor(p, 1, 16);
            p += __shfl_xor(p, 2, 16);
            p += __shfl_xor(p, 4, 16);
            p += __shfl_xor(p, 8, 16);          // p = f_j . a_dst[h]
            float l = ssrc + p;
            l = (l > 0.f) ? l : 0.2f * l;       // leaky_relu, ALPHA = 0.2
            float w = ok[k] ? __expf(fminf(l, 60.f)) : 0.f;
            den += w;
            acc[0] += w * f0; acc[1] += w * f1; acc[2] += w * f2; acc[3] += w * f3;
        }
    } else {
        // ref: all-NEG_FILL row -> uniform softmax over every node
        for (int j = wv; j < N_NODES; j += 4) {
            short4v fv = *(const short4v*)(feats + (size_t)j * C_OUT + lane * 4);
            acc[0] += bf2f(fv[0]); acc[1] += bf2f(fv[1]);
            acc[2] += bf2f(fv[2]); acc[3] += bf2f(fv[3]);
            den += 1.0f;
        }
    }
    redv[wv][lane] = acc;
    redd[wv][lane] = den;
    __syncthreads();

    if (wv == 0) {
        floatx4 r0 = redv[0][lane], r1 = redv[1][lane], r2 = redv[2][lane], r3 = redv[3][lane];
        float d = redd[0][lane] + redd[1][lane] + redd[2][lane] + redd[3][lane];
        if (d <= 0.f) d = 1.f;                  // unreachable guard
        float inv = 1.0f / d;
        floatx4 o;
        o[0] = (r0[0] + r1[0] + r2[0] + r3[0]) * inv;
        o[1] = (r0[1] + r1[1] + r2[1] + r3[1]) * inv;
        o[2] = (r0[2] + r1[2] + r2[2] + r3[2]) * inv;
        o[3] = (r0[3] + r1[3] + r2[3] + r3[3]) * inv;
        *(floatx4*)(out + (size_t)i * C_OUT + lane * 4) = o;
    }
}

extern "C" void kernel_launch(void* const* d_in, const int* in_sizes, int n_in,
                              void* d_out, int out_size, void* d_ws, size_t ws_size,
                              hipStream_t stream) {
    const float* x  = (const float*)d_in[0];
    const int*   ei = (const int*)d_in[1];
    const float* W  = (const float*)d_in[2];
    const float* b  = (const float*)d_in[3];
    const float* a  = (const float*)d_in[4];
    float* out = (float*)d_out;

    // Workspace layout (ws_size is 256 MB; we use ~3 MB):
    //   feats @ 0      : 2 MB (bf16 4096x256)
    //   nbr   @ 2 MB   : 1 MB (u16 4096x128)
    //   deg   @ 3 MB   : 16 KB
    uint8_t* ws = (uint8_t*)d_ws;
    __hip_bfloat16* feats = (__hip_bfloat16*)ws;
    unsigned short* nbr   = (unsigned short*)(ws + (2u << 20));
    int*            deg   = (int*)(ws + (3u << 20));

    hipMemsetAsync(deg, 0, N_NODES * sizeof(int), stream);
    k1_gemm_scatter<<<GEMM_BLOCKS + SCAT_BLOCKS, 256, 0, stream>>>(x, W, b, ei, nbr, deg, feats);
    aggregate<<<N_NODES, 256, 0, stream>>>(nbr, deg, feats, a, out);
}

// Round 11
// 102.063 us; speedup vs baseline: 1.1628x; 1.0033x over previous
//
#include <hip/hip_runtime.h>
#include <hip/hip_bf16.h>
#include <stdint.h>

#define N_NODES 4096
#define N_EDGES 131072
#define C_IN 256
#define C_OUT 256
#define N_HEADS 4
#define C_HEAD 64
#define MAX_DEG 128
#define GEMM_BLOCKS 1024
#define SCAT_BLOCKS 128

typedef __attribute__((ext_vector_type(8))) short short8;
typedef __attribute__((ext_vector_type(4))) short short4v;
typedef __attribute__((ext_vector_type(4))) float floatx4;

union f32u { float f; uint32_t u; };
__device__ __forceinline__ float bf2f(short s) {
    f32u v; v.u = ((uint32_t)(uint16_t)s) << 16; return v.f;
}
__device__ __forceinline__ short f2bf(float f) {
    __hip_bfloat16 h = __float2bfloat16(f);
    return *reinterpret_cast<short*>(&h);
}

// ---- K1: scatter (blocks 1024..1151) in parallel with gemm (blocks 0..1023) ----
// gemm: feats = x @ W^T + b (fp32 in, bf16 MFMA fp32-accum, bf16 out)
// scatter: capped CSR from edge_index (dedup at aggregation)
__global__ __launch_bounds__(256) void k1_gemm_scatter(
    const float* __restrict__ x, const float* __restrict__ W,
    const float* __restrict__ b, const int* __restrict__ ei,
    unsigned short* __restrict__ nbr, int* __restrict__ deg,
    __hip_bfloat16* __restrict__ feats)
{
    int blk = blockIdx.x;
    int tid = threadIdx.x;
    if (blk < GEMM_BLOCKS) {
        int lane = tid & 63;
        int wave = tid >> 6;
        int tile = blk * 4 + wave;                 // 4096 tiles
        int row0 = (tile >> 4) * 16;
        int col0 = (tile & 15) * 16;
        int r    = lane & 15;
        int quad = lane >> 4;

        const floatx4* ax = (const floatx4*)(x + (size_t)(row0 + r) * C_IN);
        const floatx4* bw = (const floatx4*)(W + (size_t)(col0 + r) * C_IN);

        floatx4 acc = {0.f, 0.f, 0.f, 0.f};
        #pragma unroll
        for (int k8 = 0; k8 < 8; ++k8) {           // K=256, steps of 32; frag k = quad*8+j
            floatx4 a0 = ax[k8 * 8 + quad * 2], a1 = ax[k8 * 8 + quad * 2 + 1];
            floatx4 b0 = bw[k8 * 8 + quad * 2], b1 = bw[k8 * 8 + quad * 2 + 1];
            short8 av, bq;
            #pragma unroll
            for (int j = 0; j < 4; ++j) {
                av[j] = f2bf(a0[j]); av[4 + j] = f2bf(a1[j]);
                bq[j] = f2bf(b0[j]); bq[4 + j] = f2bf(b1[j]);
            }
            acc = __builtin_amdgcn_mfma_f32_16x16x32_bf16(av, bq, acc, 0, 0, 0);
        }
        // C/D layout: col = lane&15, row = quad*4 + reg (HW-verified)
        int gn = col0 + r;
        float bias = b[gn];
        #pragma unroll
        for (int rr = 0; rr < 4; ++rr) {
            int gm = row0 + quad * 4 + rr;
            feats[(size_t)gm * C_OUT + gn] = __float2bfloat16(acc[rr] + bias);
        }
    } else {
        // scatter: 128 blocks x 256 thr x 4 edges
        // int64 edge_index (ref dtype): odd int32 words are all 0 (uniform scalar loads)
        bool is64 = true;
        #pragma unroll
        for (int q = 1; q < 64; q += 2) is64 = is64 && (ei[q] == 0);
        int base = (blk - GEMM_BLOCKS) * 256 + tid;      // 0..32767
        #pragma unroll
        for (int qq = 0; qq < 4; ++qq) {
            int e = base + qq * (SCAT_BLOCKS * 256);
            int row, col;
            if (is64) {
                const long long* e64 = (const long long*)ei;
                row = (int)e64[e];            // edge_index[0, e] -> output row i
                col = (int)e64[N_EDGES + e];  // edge_index[1, e] -> neighbor j
            } else {
                row = ei[e];
                col = ei[N_EDGES + e];
            }
            int pos = atomicAdd(&deg[row], 1);
            if (pos < MAX_DEG) nbr[row * MAX_DEG + pos] = (unsigned short)col;
        }
    }
}

// ---- K2: fused scores + softmax + aggregation ----
// Block = 256 thr = 4 waves, one block per node i.
// Lane owns channels 4*lane..4*lane+3 (head h = lane>>4).
// Wave w handles neighbors k = w, w+4, ...; score f_j.a_dst computed in-loop
// via 16-lane (per-head) shfl_xor reduce; cross-wave reduce in LDS.
// Dedup via shared bitmap + atomicOr: duplicates carry identical (j, weight),
// so keep-exactly-one == reference's boolean-adjacency semantics.
__global__ __launch_bounds__(256) void aggregate(
    const unsigned short* __restrict__ nbr,
    const int* __restrict__ deg,
    const __hip_bfloat16* __restrict__ feats,
    const float* __restrict__ a,
    float* __restrict__ out)
{
    int i    = blockIdx.x;
    int t    = threadIdx.x;
    int wv   = t >> 6;
    int lane = t & 63;
    int h    = lane >> 4;
    int li   = lane & 15;

    __shared__ unsigned short lst[MAX_DEG];
    __shared__ unsigned char  ok[MAX_DEG];
    __shared__ uint32_t       bmap[N_NODES / 32];   // 512 B
    __shared__ float          ssrc_sh[N_HEADS];
    __shared__ floatx4        redv[4][64];
    __shared__ float          redd[4][64];

    int n = deg[i];
    n = (n < MAX_DEG) ? n : MAX_DEG;

    if (t < n) lst[t] = nbr[i * MAX_DEG + t];
    if (t < N_NODES / 32) bmap[t] = 0u;
    __syncthreads();

    // O(1) dedup + s_src in the same phase
    if (t < n) {
        int j = lst[t];
        uint32_t bit = 1u << (j & 31);
        uint32_t old = atomicOr(&bmap[j >> 5], bit);
        ok[t] = (old & bit) ? 0 : 1;
    }

    // per-lane slices of the attention vector (a[h][0:64]=src, a[h][64:128]=dst)
    floatx4 as4 = *(const floatx4*)(a + h * 2 * C_HEAD + 4 * li);
    floatx4 ad4 = *(const floatx4*)(a + h * 2 * C_HEAD + C_HEAD + 4 * li);

    if (wv == 0) {   // s_src[i,h]: one row read + per-head reduce
        short4v fi = *(const short4v*)(feats + (size_t)i * C_OUT + lane * 4);
        float p = bf2f(fi[0]) * as4[0] + bf2f(fi[1]) * as4[1]
                + bf2f(fi[2]) * as4[2] + bf2f(fi[3]) * as4[3];
        p += __shfl_xor(p, 1, 16);
        p += __shfl_xor(p, 2, 16);
        p += __shfl_xor(p, 4, 16);
        p += __shfl_xor(p, 8, 16);
        if (li == 0) ssrc_sh[h] = p;
    }
    __syncthreads();     // publishes ok[] and ssrc_sh

    float ssrc = ssrc_sh[h];
    floatx4 acc = {0.f, 0.f, 0.f, 0.f};
    float   den = 0.f;

    if (n > 0) {
        #pragma unroll 2
        for (int k = wv; k < n; k += 4) {
            int j = lst[k];
            short4v fv = *(const short4v*)(feats + (size_t)j * C_OUT + lane * 4);
            float f0 = bf2f(fv[0]), f1 = bf2f(fv[1]), f2 = bf2f(fv[2]), f3 = bf2f(fv[3]);
            float p = f0 * ad4[0] + f1 * ad4[1] + f2 * ad4[2] + f3 * ad4[3];
            p += __shfl_xor(p, 1, 16);
            p += __shfl_xor(p, 2, 16);
            p += __shfl_xor(p, 4, 16);
            p += __shfl_xor(p, 8, 16);          // p = f_j . a_dst[h]
            float l = ssrc + p;
            l = (l > 0.f) ? l : 0.2f * l;       // leaky_relu, ALPHA = 0.2
            float w = ok[k] ? __expf(fminf(l, 60.f)) : 0.f;
            den += w;
            acc[0] += w * f0; acc[1] += w * f1; acc[2] += w * f2; acc[3] += w * f3;
        }
    } else {
        // ref: all-NEG_FILL row -> uniform softmax over every node
        for (int j = wv; j < N_NODES; j += 4) {
            short4v fv = *(const short4v*)(feats + (size_t)j * C_OUT + lane * 4);
            acc[0] += bf2f(fv[0]); acc[1] += bf2f(fv[1]);
            acc[2] += bf2f(fv[2]); acc[3] += bf2f(fv[3]);
            den += 1.0f;
        }
    }
    redv[wv][lane] = acc;
    redd[wv][lane] = den;
    __syncthreads();

    if (wv == 0) {
        floatx4 r0 = redv[0][lane], r1 = redv[1][lane], r2 = redv[2][lane], r3 = redv[3][lane];
        float d = redd[0][lane] + redd[1][lane] + redd[2][lane] + redd[3][lane];
        if (d <= 0.f) d = 1.f;                  // unreachable guard
        float inv = 1.0f / d;
        floatx4 o;
        o[0] = (r0[0] + r1[0] + r2[0] + r3[0]) * inv;
        o[1] = (r0[1] + r1[1] + r2[1] + r3[1]) * inv;
        o[2] = (r0[2] + r1[2] + r2[2] + r3[2]) * inv;
        o[3] = (r0[3] + r1[3] + r2[3] + r3[3]) * inv;
        *(floatx4*)(out + (size_t)i * C_OUT + lane * 4) = o;
    }
}

extern "C" void kernel_launch(void* const* d_in, const int* in_sizes, int n_in,
                              void* d_out, int out_size, void* d_ws, size_t ws_size,
                              hipStream_t stream) {
    const float* x  = (const float*)d_in[0];
    const int*   ei = (const int*)d_in[1];
    const float* W  = (const float*)d_in[2];
    const float* b  = (const float*)d_in[3];
    const float* a  = (const float*)d_in[4];
    float* out = (float*)d_out;

    // Workspace layout (ws_size is 256 MB; we use ~3 MB):
    //   feats @ 0      : 2 MB (bf16 4096x256)
    //   nbr   @ 2 MB   : 1 MB (u16 4096x128)
    //   deg   @ 3 MB   : 16 KB
    uint8_t* ws = (uint8_t*)d_ws;
    __hip_bfloat16* feats = (__hip_bfloat16*)ws;
    unsigned short* nbr   = (unsigned short*)(ws + (2u << 20));
    int*            deg   = (int*)(ws + (3u << 20));

    hipMemsetAsync(deg, 0, N_NODES * sizeof(int), stream);
    k1_gemm_scatter<<<GEMM_BLOCKS + SCAT_BLOCKS, 256, 0, stream>>>(x, W, b, ei, nbr, deg, feats);
    aggregate<<<N_NODES, 256, 0, stream>>>(nbr, deg, feats, a, out);
}